// Round 5
// baseline (3797.625 us; speedup 1.0000x reference)
//
#include <hip/hip_runtime.h>
#include <cstdint>
#include <cstddef>

#define B_  64
#define T_  512
#define S_  512
#define D_  256

#define GROUPS 16
#define BPG    16

typedef __attribute__((ext_vector_type(4))) float f32x4;
typedef __attribute__((ext_vector_type(8))) short bf16x8;

// ---- helpers ----
__device__ __forceinline__ ushort f2bf(float f) {
    union { float f; uint32_t u; } v; v.f = f;
    uint32_t r = v.u + 0x7FFFu + ((v.u >> 16) & 1u);
    return (ushort)(r >> 16);
}
__device__ __forceinline__ float bf2f(ushort h) {
    union { uint32_t u; float f; } v; v.u = ((uint32_t)h) << 16; return v.f;
}
__device__ __forceinline__ float4 ldx4_cg(const float* p) {
    float4 r;
    asm volatile("global_load_dwordx4 %0, %1, off sc0 sc1\n\ts_waitcnt vmcnt(0)"
                 : "=v"(r) : "v"(p) : "memory");
    return r;
}
__device__ __forceinline__ void st_cg(float* p, float v) {
    asm volatile("global_store_dword %0, %1, off sc0 sc1" :: "v"(p), "v"(v) : "memory");
}
__device__ __forceinline__ bool rdy4(float4 v, float rb) {
    return __builtin_fabsf(v.x - rb) < 1.5f && __builtin_fabsf(v.y - rb) < 1.5f &&
           __builtin_fabsf(v.z - rb) < 1.5f && __builtin_fabsf(v.w - rb) < 1.5f;
}

__global__ __launch_bounds__(256) void ws_init(float* __restrict__ hbuf) {
    int i = blockIdx.x * 256 + threadIdx.x;
    if (i < 2 * 16384) hbuf[i] = 0.f;
}

// ==================== LSTM: weights in registers ====================
// 256 blocks x 512 threads. block = (grp, jb). thread = (blc, dlc, ks):
//   blc = tid>>7 (batch in group), dlc = (tid>>3)&15 (dim in 16-chunk), ks = tid&7 (k-eighth)
// Each thread holds Wc[4 gate rows][32 k] in 128 VGPRs.

__global__ __launch_bounds__(512, 2) void lstm_persistent(
    const float* __restrict__ de,  const float* __restrict__ h0,
    const float* __restrict__ c0,
    const float* __restrict__ Wih, const float* __restrict__ Whh,
    const float* __restrict__ bih, const float* __restrict__ bhh,
    float* __restrict__ out, float* __restrict__ hbuf)
{
    __shared__ float hlds[4 * 288];   // [blc][ks*36 + j*4 + e]  (swizzled, conflict-free)

    const int tid = threadIdx.x;
    const int grp = blockIdx.x >> 4;
    const int jb  = blockIdx.x & 15;

    const int blc = tid >> 7;
    const int dlc = (tid >> 3) & 15;
    const int ks  = tid & 7;

    const int bx = grp * 4 + blc;
    const int dx = jb * 16 + dlc;

    const int r0 = jb * 16 + dlc;
    const int r1 = 256 + r0, r2 = 512 + r0, r3 = 768 + r0;

    const float b0 = bih[r0] + bhh[r0];
    const float b1 = bih[r1] + bhh[r1];
    const float b2 = bih[r2] + bhh[r2];
    const float b3 = bih[r3] + bhh[r3];

    float c_reg = c0[(size_t)bx * 256 + dx];   // all ks lanes redundant (consistent)

    const float4* Wih4 = (const float4*)Wih;
    const float4* Whh4 = (const float4*)Whh;

    float4 w0[8], w1[8], w2[8], w3[8];         // Wc slices, filled after t=0

    const float* hr = hlds + blc * 288 + ks * 36;

    for (int t = 0; t < T_; ++t) {
        float a0 = 0.f, a1 = 0.f, a2 = 0.f, a3 = 0.f;

        if (t == 0) {
            // ---- stage h0, dot with Whh (global), stage e0, dot with Wih ----
            if (tid < 256) {
                float4 v = *(const float4*)(h0 + (size_t)(grp * 4 + (tid >> 6)) * 256 + (tid & 63) * 4);
                *(float4*)(hlds + (tid >> 6) * 288 + ((tid & 63) >> 3) * 36 + (tid & 7) * 4) = v;
            }
            __syncthreads();
            #pragma unroll
            for (int j = 0; j < 8; ++j) {
                float4 h = *(const float4*)(hr + 4 * j);
                float4 x;
                x = Whh4[(size_t)r0 * 64 + ks * 8 + j]; a0 += x.x*h.x + x.y*h.y + x.z*h.z + x.w*h.w;
                x = Whh4[(size_t)r1 * 64 + ks * 8 + j]; a1 += x.x*h.x + x.y*h.y + x.z*h.z + x.w*h.w;
                x = Whh4[(size_t)r2 * 64 + ks * 8 + j]; a2 += x.x*h.x + x.y*h.y + x.z*h.z + x.w*h.w;
                x = Whh4[(size_t)r3 * 64 + ks * 8 + j]; a3 += x.x*h.x + x.y*h.y + x.z*h.z + x.w*h.w;
            }
            __syncthreads();
            if (tid < 256) {
                float4 v = *(const float4*)(de + (size_t)(grp * 4 + (tid >> 6)) * T_ * D_ + (tid & 63) * 4);
                *(float4*)(hlds + (tid >> 6) * 288 + ((tid & 63) >> 3) * 36 + (tid & 7) * 4) = v;
            }
            __syncthreads();
            #pragma unroll
            for (int j = 0; j < 8; ++j) {
                float4 h = *(const float4*)(hr + 4 * j);
                float4 x;
                x = Wih4[(size_t)r0 * 64 + ks * 8 + j]; a0 += x.x*h.x + x.y*h.y + x.z*h.z + x.w*h.w;
                x = Wih4[(size_t)r1 * 64 + ks * 8 + j]; a1 += x.x*h.x + x.y*h.y + x.z*h.z + x.w*h.w;
                x = Wih4[(size_t)r2 * 64 + ks * 8 + j]; a2 += x.x*h.x + x.y*h.y + x.z*h.z + x.w*h.w;
                x = Wih4[(size_t)r3 * 64 + ks * 8 + j]; a3 += x.x*h.x + x.y*h.y + x.z*h.z + x.w*h.w;
            }
        } else {
            // ---- dataflow poll of h_{t-1}, then register-weight dot ----
            if (tid < 256) {
                const float rb = 4.0f + 4.0f * (float)(((t - 1) >> 1) & 1);
                const float* hp = hbuf + ((t - 1) & 1) * 16384 + grp * 1024 + tid * 4;
                float4 v = ldx4_cg(hp);
                while (!rdy4(v, rb)) v = ldx4_cg(hp);
                *(float4*)(hlds + (tid >> 6) * 288 + ((tid & 63) >> 3) * 36 + (tid & 7) * 4) =
                    make_float4(v.x - rb, v.y - rb, v.z - rb, v.w - rb);
            }
            __syncthreads();
            #pragma unroll
            for (int j = 0; j < 8; ++j) {
                float4 h = *(const float4*)(hr + 4 * j);
                a0 += w0[j].x*h.x + w0[j].y*h.y + w0[j].z*h.z + w0[j].w*h.w;
                a1 += w1[j].x*h.x + w1[j].y*h.y + w1[j].z*h.z + w1[j].w*h.w;
                a2 += w2[j].x*h.x + w2[j].y*h.y + w2[j].z*h.z + w2[j].w*h.w;
                a3 += w3[j].x*h.x + w3[j].y*h.y + w3[j].z*h.z + w3[j].w*h.w;
            }
        }

        // k-eighth reduction across ks lanes (xor 1,2,4)
        a0 += __shfl_xor(a0, 1); a0 += __shfl_xor(a0, 2); a0 += __shfl_xor(a0, 4);
        a1 += __shfl_xor(a1, 1); a1 += __shfl_xor(a1, 2); a1 += __shfl_xor(a1, 4);
        a2 += __shfl_xor(a2, 1); a2 += __shfl_xor(a2, 2); a2 += __shfl_xor(a2, 4);
        a3 += __shfl_xor(a3, 1); a3 += __shfl_xor(a3, 2); a3 += __shfl_xor(a3, 4);

        // gate math (all lanes redundant; only ks==0 stores)
        {
            float gi = a0 + b0, gf = a1 + b1, gg = a2 + b2, go = a3 + b3;
            float si = 1.f / (1.f + __expf(-gi));
            float sf = 1.f / (1.f + __expf(-gf));
            float so = 1.f / (1.f + __expf(-go));
            float tg = 1.f - 2.f / (1.f + __expf(2.f * gg));
            c_reg = sf * c_reg + si * tg;
            float tc = 1.f - 2.f / (1.f + __expf(2.f * c_reg));
            float hn = so * tc;
            if (ks == 0) {
                if (t < T_ - 1) {
                    float wb = 4.0f + 4.0f * (float)((t >> 1) & 1);
                    st_cg(hbuf + (t & 1) * 16384 + (size_t)bx * 256 + dx, hn + wb);
                }
                out[((size_t)bx * T_ + t) * 512 + dx] = hn;
            }
        }

        if (t == 0) {
            // load Wc = Wih + Whh into registers (one-time)
            #pragma unroll
            for (int j = 0; j < 8; ++j) {
                int o = ks * 8 + j;
                float4 x, y;
                x = Wih4[(size_t)r0 * 64 + o]; y = Whh4[(size_t)r0 * 64 + o];
                w0[j] = make_float4(x.x + y.x, x.y + y.y, x.z + y.z, x.w + y.w);
                x = Wih4[(size_t)r1 * 64 + o]; y = Whh4[(size_t)r1 * 64 + o];
                w1[j] = make_float4(x.x + y.x, x.y + y.y, x.z + y.z, x.w + y.w);
                x = Wih4[(size_t)r2 * 64 + o]; y = Whh4[(size_t)r2 * 64 + o];
                w2[j] = make_float4(x.x + y.x, x.y + y.y, x.z + y.z, x.w + y.w);
                x = Wih4[(size_t)r3 * 64 + o]; y = Whh4[(size_t)r3 * 64 + o];
                w3[j] = make_float4(x.x + y.x, x.y + y.y, x.z + y.z, x.w + y.w);
            }
        }
        __syncthreads();   // protect hlds before next stage
    }
}

// ==================== Attention: bf16 MFMA flash ====================
// block = (b, 64-t tile), 256 threads = 4 waves, wave owns 16 t-rows.
// H in registers as hi/lo bf16 A-frags. Per 32-s chunk: stage E bf16 (row-major
// + transposed), scores via MFMA, online softmax in regs, P hi/lo -> PV MFMA.

__global__ __launch_bounds__(256, 2) void attn_kernel(
    const float* __restrict__ E, float* __restrict__ out)
{
    __shared__ alignas(16) ushort Ech [32 * 264];    // [s][k] bf16
    __shared__ alignas(16) ushort EchT[256 * 40];    // [d][s] bf16
    __shared__ alignas(16) ushort Phi[4][16 * 40];   // per-wave P hi
    __shared__ alignas(16) ushort Plo[4][16 * 40];   // per-wave P lo

    const int id  = blockIdx.x;          // XCD-swizzled decode
    const int xcd = id & 7, rr = id >> 3;
    const int tt  = rr & 7,  bh = rr >> 3;
    const int b   = bh * 8 + xcd;
    const int t0  = tt * 64;

    const int tid = threadIdx.x;
    const int w   = tid >> 6;
    const int l   = tid & 63;
    const int lr  = l & 15;
    const int lg  = l >> 4;

    // ---- H A-frags (hi/lo split), 8 k-tiles ----
    bf16x8 Ahi[8], Alo[8];
    {
        const float* Hrow = out + ((size_t)b * T_ + (t0 + w * 16 + lr)) * 512;
        #pragma unroll
        for (int kt = 0; kt < 8; ++kt) {
            float4 x0 = *(const float4*)(Hrow + kt * 32 + lg * 8);
            float4 x1 = *(const float4*)(Hrow + kt * 32 + lg * 8 + 4);
            float f[8] = {x0.x, x0.y, x0.z, x0.w, x1.x, x1.y, x1.z, x1.w};
            bf16x8 hi, lo;
            #pragma unroll
            for (int j = 0; j < 8; ++j) {
                ushort h = f2bf(f[j]);
                hi[j] = (short)h;
                lo[j] = (short)f2bf(f[j] - bf2f(h));
            }
            Ahi[kt] = hi; Alo[kt] = lo;
        }
    }

    f32x4 ctx[16];
    #pragma unroll
    for (int i = 0; i < 16; ++i) ctx[i] = (f32x4){0.f, 0.f, 0.f, 0.f};
    float mrow[4] = {-1e30f, -1e30f, -1e30f, -1e30f};
    float srow[4] = {0.f, 0.f, 0.f, 0.f};

    const float* Eb = E + (size_t)b * S_ * 256;

    for (int c = 0; c < 16; ++c) {
        // ---- stage Ech[s][k] from global ----
        #pragma unroll
        for (int m = 0; m < 8; ++m) {
            int idx = m * 256 + tid;
            int sr = idx >> 6, k4 = idx & 63;
            float4 e = *(const float4*)(Eb + (size_t)(c * 32 + sr) * 256 + 4 * k4);
            ushort4 u;
            u.x = f2bf(e.x); u.y = f2bf(e.y); u.z = f2bf(e.z); u.w = f2bf(e.w);
            *(ushort4*)(&Ech[sr * 264 + 4 * k4]) = u;
        }
        __syncthreads();

        // ---- scores MFMA (hi+lo into same acc) ----
        f32x4 sacc0 = (f32x4){0.f,0.f,0.f,0.f};
        f32x4 sacc1 = (f32x4){0.f,0.f,0.f,0.f};
        #pragma unroll
        for (int kt = 0; kt < 8; ++kt) {
            bf16x8 Bf0 = *(const bf16x8*)(&Ech[(0 * 16 + lr) * 264 + kt * 32 + lg * 8]);
            bf16x8 Bf1 = *(const bf16x8*)(&Ech[(1 * 16 + lr) * 264 + kt * 32 + lg * 8]);
            sacc0 = __builtin_amdgcn_mfma_f32_16x16x32_bf16(Ahi[kt], Bf0, sacc0, 0, 0, 0);
            sacc0 = __builtin_amdgcn_mfma_f32_16x16x32_bf16(Alo[kt], Bf0, sacc0, 0, 0, 0);
            sacc1 = __builtin_amdgcn_mfma_f32_16x16x32_bf16(Ahi[kt], Bf1, sacc1, 0, 0, 0);
            sacc1 = __builtin_amdgcn_mfma_f32_16x16x32_bf16(Alo[kt], Bf1, sacc1, 0, 0, 0);
        }

        // ---- stage EchT[d][s] from Ech (lane-consecutive-s writes) ----
        #pragma unroll
        for (int m = 0; m < 8; ++m) {
            int idx = m * 256 + tid;
            int s = idx & 31, kq = idx >> 5;    // kq 0..63
            ushort4 v = *(const ushort4*)(&Ech[s * 264 + 4 * kq]);
            EchT[(4 * kq + 0) * 40 + s] = v.x;
            EchT[(4 * kq + 1) * 40 + s] = v.y;
            EchT[(4 * kq + 2) * 40 + s] = v.z;
            EchT[(4 * kq + 3) * 40 + s] = v.w;
        }

        // ---- online softmax (lane: 4 reg-rows x 2 cols) ----
        float cmax[4], p0[4], p1[4], csum[4], mnew[4], scale[4];
        #pragma unroll
        for (int g = 0; g < 4; ++g) cmax[g] = fmaxf(sacc0[g], sacc1[g]);
        #pragma unroll
        for (int d = 1; d < 16; d <<= 1) {
            #pragma unroll
            for (int g = 0; g < 4; ++g) cmax[g] = fmaxf(cmax[g], __shfl_xor(cmax[g], d));
        }
        #pragma unroll
        for (int g = 0; g < 4; ++g) {
            mnew[g]  = fmaxf(mrow[g], cmax[g]);
            scale[g] = __expf(mrow[g] - mnew[g]);
            p0[g] = __expf(sacc0[g] - mnew[g]);
            p1[g] = __expf(sacc1[g] - mnew[g]);
            csum[g] = p0[g] + p1[g];
        }
        #pragma unroll
        for (int d = 1; d < 16; d <<= 1) {
            #pragma unroll
            for (int g = 0; g < 4; ++g) csum[g] += __shfl_xor(csum[g], d);
        }
        #pragma unroll
        for (int g = 0; g < 4; ++g) {
            srow[g] = srow[g] * scale[g] + csum[g];
            mrow[g] = mnew[g];
        }
        #pragma unroll
        for (int i = 0; i < 16; ++i) {
            ctx[i][0] *= scale[0]; ctx[i][1] *= scale[1];
            ctx[i][2] *= scale[2]; ctx[i][3] *= scale[3];
        }
        // write P hi/lo (row = lg*4+g, col = ct*16+lr)
        #pragma unroll
        for (int g = 0; g < 4; ++g) {
            int rrw = (lg * 4 + g) * 40;
            ushort h0v = f2bf(p0[g]);
            Phi[w][rrw + lr]      = h0v;
            Plo[w][rrw + lr]      = f2bf(p0[g] - bf2f(h0v));
            ushort h1v = f2bf(p1[g]);
            Phi[w][rrw + 16 + lr] = h1v;
            Plo[w][rrw + 16 + lr] = f2bf(p1[g] - bf2f(h1v));
        }
        __syncthreads();   // EchT + P ready

        // ---- PV MFMA ----
        {
            bf16x8 Ap = *(const bf16x8*)(&Phi[w][lr * 40 + lg * 8]);
            bf16x8 Aq = *(const bf16x8*)(&Plo[w][lr * 40 + lg * 8]);
            #pragma unroll
            for (int dt = 0; dt < 16; ++dt) {
                bf16x8 Bf = *(const bf16x8*)(&EchT[(dt * 16 + lr) * 40 + lg * 8]);
                ctx[dt] = __builtin_amdgcn_mfma_f32_16x16x32_bf16(Ap, Bf, ctx[dt], 0, 0, 0);
                ctx[dt] = __builtin_amdgcn_mfma_f32_16x16x32_bf16(Aq, Bf, ctx[dt], 0, 0, 0);
            }
        }
        __syncthreads();   // PV done before next-chunk restage
    }

    // ---- epilogue: divide by row sums, store ctx ----
    float inv[4];
    #pragma unroll
    for (int g = 0; g < 4; ++g) inv[g] = 1.f / srow[g];
    #pragma unroll
    for (int dt = 0; dt < 16; ++dt) {
        #pragma unroll
        for (int g = 0; g < 4; ++g) {
            out[((size_t)b * T_ + (t0 + w * 16 + lg * 4 + g)) * 512 + 256 + dt * 16 + lr] =
                ctx[dt][g] * inv[g];
        }
    }
}

// -------------------- launch --------------------

extern "C" void kernel_launch(void* const* d_in, const int* in_sizes, int n_in,
                              void* d_out, int out_size, void* d_ws, size_t ws_size,
                              hipStream_t stream)
{
    const float* de  = (const float*)d_in[0];
    const float* h0  = (const float*)d_in[1];
    const float* c0  = (const float*)d_in[2];
    const float* E   = (const float*)d_in[3];
    const float* Wih = (const float*)d_in[4];
    const float* Whh = (const float*)d_in[5];
    const float* bih = (const float*)d_in[6];
    const float* bhh = (const float*)d_in[7];
    float* out  = (float*)d_out;
    float* hbuf = (float*)d_ws;

    ws_init<<<128, 256, 0, stream>>>(hbuf);

    void* args[] = {(void*)&de, (void*)&h0, (void*)&c0, (void*)&Wih, (void*)&Whh,
                    (void*)&bih, (void*)&bhh, (void*)&out, (void*)&hbuf};
    hipLaunchCooperativeKernel((const void*)lstm_persistent,
                               dim3(GROUPS * BPG), dim3(512), args, 0, stream);

    attn_kernel<<<dim3(512), 256, 0, stream>>>(E, out);
}

// Round 6
// 1186.895 us; speedup vs baseline: 3.1996x; 3.1996x over previous
//
#include <hip/hip_runtime.h>
#include <cstdint>
#include <cstddef>

#define B_  64
#define T_  512
#define S_  512
#define D_  256

#define GROUPS 16
#define BPG    16

typedef __attribute__((ext_vector_type(4))) float f32x4;
typedef __attribute__((ext_vector_type(8))) short bf16x8;

union UBF { bf16x8 v; uint32_t u[4]; };
union USH { bf16x8 v; ushort s[8]; };

// ---- helpers ----
__device__ __forceinline__ ushort f2bf(float f) {
    union { float f; uint32_t u; } v; v.f = f;
    uint32_t r = v.u + 0x7FFFu + ((v.u >> 16) & 1u);
    return (ushort)(r >> 16);
}
__device__ __forceinline__ float bf2f(ushort h) {
    union { uint32_t u; float f; } v; v.u = ((uint32_t)h) << 16; return v.f;
}
__device__ __forceinline__ uint4 ldx4u_cg(const uint32_t* p) {
    uint4 r;
    asm volatile("global_load_dwordx4 %0, %1, off sc0 sc1\n\ts_waitcnt vmcnt(0)"
                 : "=v"(r) : "v"(p) : "memory");
    return r;
}
__device__ __forceinline__ void st_cg_u32(uint32_t* p, uint32_t v) {
    asm volatile("global_store_dword %0, %1, off sc0 sc1" :: "v"(p), "v"(v) : "memory");
}

// hbuf ring: 2 slots x 16384 u32 ([slot][b][d]); packed = hi16 | (lo16&~3) | cnt
// cnt = (t>>1)%3; init 0xFFFFFFFF (cnt bits = 3, never matches)
__global__ __launch_bounds__(256) void ws_init(uint32_t* __restrict__ hbuf) {
    int i = blockIdx.x * 256 + threadIdx.x;
    if (i < 2 * 16384)
        __hip_atomic_store(hbuf + i, 0xFFFFFFFFu, __ATOMIC_RELAXED, __HIP_MEMORY_SCOPE_AGENT);
}

// ==================== LSTM: MFMA with Wc as bf16 hi/lo A-frags ====================
// 256 blocks x 256 threads. block = (grp 0..15, jb 0..15). wave w = gate w,
// owning 16 gate-rows (dims jb*16..+16). A-frags: 8 ksteps x {hi,lo} = 64 VGPR.

__global__ __launch_bounds__(256, 1) void lstm_persistent(
    const float* __restrict__ de,  const float* __restrict__ h0,
    const float* __restrict__ c0,
    const float* __restrict__ Wih, const float* __restrict__ Whh,
    const float* __restrict__ bih, const float* __restrict__ bhh,
    float* __restrict__ out, uint32_t* __restrict__ hbuf)
{
    __shared__ uint32_t hlds[4 * 264];     // packed h, [b][d] stride 264
    __shared__ float    glds[256];         // gates [gate][dlc][b]
    __shared__ float    t0buf[2][4][256];  // e0, h0

    const int tid = threadIdx.x;
    const int grp = blockIdx.x >> 4;
    const int jb  = blockIdx.x & 15;

    const int w  = tid >> 6;    // wave = gate
    const int l  = tid & 63;
    const int lr = l & 15;      // A row (dlc) / D col (batch if <4)
    const int lg = l >> 4;

    // combine-lane mapping (tid < 64): b = tid&3, dlc = tid>>2
    const int cb  = tid & 3;
    const int cd  = tid >> 2;
    const int bx  = grp * 4 + cb;
    const int dxc = jb * 16 + cd;

    float c_reg = 0.f;
    float bsum0 = 0.f, bsum1 = 0.f, bsum2 = 0.f, bsum3 = 0.f;
    if (tid < 64) {
        c_reg = c0[(size_t)bx * 256 + dxc];
        bsum0 = bih[          jb * 16 + cd] + bhh[          jb * 16 + cd];
        bsum1 = bih[256 +     jb * 16 + cd] + bhh[256 +     jb * 16 + cd];
        bsum2 = bih[512 +     jb * 16 + cd] + bhh[512 +     jb * 16 + cd];
        bsum3 = bih[768 +     jb * 16 + cd] + bhh[768 +     jb * 16 + cd];
    }

    bf16x8 Ahi[8], Alo[8];

    // ---- t = 0: stage e0/h0, scalar dot into glds ----
    #pragma unroll
    for (int m = 0; m < 8; ++m) {
        int idx = m * 256 + tid;
        int arr = idx >> 10, bl = (idx >> 8) & 3, k = idx & 255;
        t0buf[arr][bl][k] = arr ? h0[(size_t)(grp * 4 + bl) * 256 + k]
                                : de[(size_t)(grp * 4 + bl) * T_ * D_ + k];
    }
    __syncthreads();
    {
        int r = tid >> 2, bq = tid & 3;
        int gr = (r >> 4) * 256 + jb * 16 + (r & 15);
        const float4* wi4 = (const float4*)(Wih + (size_t)gr * 256);
        const float4* wh4 = (const float4*)(Whh + (size_t)gr * 256);
        const float4* e4  = (const float4*)(&t0buf[0][bq][0]);
        const float4* h4  = (const float4*)(&t0buf[1][bq][0]);
        float a0 = 0.f, a1 = 0.f, a2 = 0.f, a3 = 0.f;
        #pragma unroll 8
        for (int k4 = 0; k4 < 64; ++k4) {
            float4 x = wi4[k4], y = e4[k4];
            a0 += x.x*y.x; a1 += x.y*y.y; a2 += x.z*y.z; a3 += x.w*y.w;
            x = wh4[k4]; y = h4[k4];
            a0 += x.x*y.x; a1 += x.y*y.y; a2 += x.z*y.z; a3 += x.w*y.w;
        }
        glds[(r >> 4) * 64 + (r & 15) * 4 + bq] = (a0 + a1) + (a2 + a3);
    }

    for (int t = 0; t < T_; ++t) {
        if (t > 0) {
            // ---- poll packed h_{t-1} (counter bits = readiness flag) ----
            const uint32_t expc = (uint32_t)(((t - 1) >> 1) % 3);
            const uint32_t* hp = hbuf + ((t - 1) & 1) * 16384 + grp * 1024 + tid * 4;
            uint4 v = ldx4u_cg(hp);
            while (((v.x & 3u) != expc) | ((v.y & 3u) != expc) |
                   ((v.z & 3u) != expc) | ((v.w & 3u) != expc))
                v = ldx4u_cg(hp);
            *(uint4*)(hlds + (tid >> 6) * 264 + (tid & 63) * 4) = v;
            __syncthreads();

            // ---- B-frags from packed LDS + MFMA ----
            f32x4 acc = (f32x4){0.f, 0.f, 0.f, 0.f};
            const uint32_t* hrow = hlds + (lr & 3) * 264 + lg * 8;
            #pragma unroll
            for (int kt = 0; kt < 8; ++kt) {
                uint4 q0 = *(const uint4*)(hrow + kt * 32);
                uint4 q1 = *(const uint4*)(hrow + kt * 32 + 4);
                UBF bh_, bl_;
                bh_.u[0] = (q0.x >> 16) | (q0.y & 0xFFFF0000u);
                bh_.u[1] = (q0.z >> 16) | (q0.w & 0xFFFF0000u);
                bh_.u[2] = (q1.x >> 16) | (q1.y & 0xFFFF0000u);
                bh_.u[3] = (q1.z >> 16) | (q1.w & 0xFFFF0000u);
                bl_.u[0] = (q0.x & 0xFFFCu) | ((q0.y & 0xFFFCu) << 16);
                bl_.u[1] = (q0.z & 0xFFFCu) | ((q0.w & 0xFFFCu) << 16);
                bl_.u[2] = (q1.x & 0xFFFCu) | ((q1.y & 0xFFFCu) << 16);
                bl_.u[3] = (q1.z & 0xFFFCu) | ((q1.w & 0xFFFCu) << 16);
                acc = __builtin_amdgcn_mfma_f32_16x16x32_bf16(Ahi[kt], bh_.v, acc, 0, 0, 0);
                acc = __builtin_amdgcn_mfma_f32_16x16x32_bf16(Alo[kt], bh_.v, acc, 0, 0, 0);
                acc = __builtin_amdgcn_mfma_f32_16x16x32_bf16(Ahi[kt], bl_.v, acc, 0, 0, 0);
            }
            if (lr < 4) {
                glds[w * 64 + (lg * 4 + 0) * 4 + lr] = acc[0];
                glds[w * 64 + (lg * 4 + 1) * 4 + lr] = acc[1];
                glds[w * 64 + (lg * 4 + 2) * 4 + lr] = acc[2];
                glds[w * 64 + (lg * 4 + 3) * 4 + lr] = acc[3];
            }
        }
        __syncthreads();

        // ---- combine: gate math, store packed h + out ----
        if (tid < 64) {
            float gi = glds[      cd * 4 + cb] + bsum0;
            float gf = glds[ 64 + cd * 4 + cb] + bsum1;
            float gg = glds[128 + cd * 4 + cb] + bsum2;
            float go = glds[192 + cd * 4 + cb] + bsum3;
            float si = 1.f / (1.f + __expf(-gi));
            float sf = 1.f / (1.f + __expf(-gf));
            float so = 1.f / (1.f + __expf(-go));
            float tg = 1.f - 2.f / (1.f + __expf(2.f * gg));
            c_reg = sf * c_reg + si * tg;
            float tc = 1.f - 2.f / (1.f + __expf(2.f * c_reg));
            float hn = so * tc;
            out[((size_t)bx * T_ + t) * 512 + dxc] = hn;
            if (t < T_ - 1) {
                uint32_t hi = (uint32_t)f2bf(hn);
                float lof   = hn - bf2f((ushort)hi);
                uint32_t lo = (uint32_t)f2bf(lof);
                uint32_t pk = (hi << 16) | (lo & 0xFFFCu) | (uint32_t)((t >> 1) % 3);
                st_cg_u32(hbuf + (t & 1) * 16384 + grp * 1024 + cb * 256 + dxc, pk);
            }
        }

        if (t == 0) {
            // ---- one-time: build Wc hi/lo A-frags ----
            int gr = w * 256 + jb * 16 + lr;
            const float4* wi4 = (const float4*)(Wih + (size_t)gr * 256);
            const float4* wh4 = (const float4*)(Whh + (size_t)gr * 256);
            #pragma unroll
            for (int kt = 0; kt < 8; ++kt) {
                float4 p  = wi4[kt * 8 + lg * 2], q  = wi4[kt * 8 + lg * 2 + 1];
                float4 r4 = wh4[kt * 8 + lg * 2], s4 = wh4[kt * 8 + lg * 2 + 1];
                float f[8] = {p.x + r4.x, p.y + r4.y, p.z + r4.z, p.w + r4.w,
                              q.x + s4.x, q.y + s4.y, q.z + s4.z, q.w + s4.w};
                USH hi, lo;
                #pragma unroll
                for (int j = 0; j < 8; ++j) {
                    ushort h = f2bf(f[j]);
                    hi.s[j] = h;
                    lo.s[j] = f2bf(f[j] - bf2f(h));
                }
                Ahi[kt] = hi.v; Alo[kt] = lo.v;
            }
        }
    }
}

// ==================== Attention: bf16 MFMA flash (unchanged, verified) ========

__global__ __launch_bounds__(256, 2) void attn_kernel(
    const float* __restrict__ E, float* __restrict__ out)
{
    __shared__ alignas(16) ushort Ech [32 * 264];
    __shared__ alignas(16) ushort EchT[256 * 40];
    __shared__ alignas(16) ushort Phi[4][16 * 40];
    __shared__ alignas(16) ushort Plo[4][16 * 40];

    const int id  = blockIdx.x;
    const int xcd = id & 7, rr = id >> 3;
    const int tt  = rr & 7,  bh = rr >> 3;
    const int b   = bh * 8 + xcd;
    const int t0  = tt * 64;

    const int tid = threadIdx.x;
    const int w   = tid >> 6;
    const int l   = tid & 63;
    const int lr  = l & 15;
    const int lg  = l >> 4;

    bf16x8 Ahi[8], Alo[8];
    {
        const float* Hrow = out + ((size_t)b * T_ + (t0 + w * 16 + lr)) * 512;
        #pragma unroll
        for (int kt = 0; kt < 8; ++kt) {
            float4 x0 = *(const float4*)(Hrow + kt * 32 + lg * 8);
            float4 x1 = *(const float4*)(Hrow + kt * 32 + lg * 8 + 4);
            float f[8] = {x0.x, x0.y, x0.z, x0.w, x1.x, x1.y, x1.z, x1.w};
            USH hi, lo;
            #pragma unroll
            for (int j = 0; j < 8; ++j) {
                ushort h = f2bf(f[j]);
                hi.s[j] = h;
                lo.s[j] = f2bf(f[j] - bf2f(h));
            }
            Ahi[kt] = hi.v; Alo[kt] = lo.v;
        }
    }

    f32x4 ctx[16];
    #pragma unroll
    for (int i = 0; i < 16; ++i) ctx[i] = (f32x4){0.f, 0.f, 0.f, 0.f};
    float mrow[4] = {-1e30f, -1e30f, -1e30f, -1e30f};
    float srow[4] = {0.f, 0.f, 0.f, 0.f};

    const float* Eb = E + (size_t)b * S_ * 256;

    for (int c = 0; c < 16; ++c) {
        #pragma unroll
        for (int m = 0; m < 8; ++m) {
            int idx = m * 256 + tid;
            int sr = idx >> 6, k4 = idx & 63;
            float4 e = *(const float4*)(Eb + (size_t)(c * 32 + sr) * 256 + 4 * k4);
            ushort4 u;
            u.x = f2bf(e.x); u.y = f2bf(e.y); u.z = f2bf(e.z); u.w = f2bf(e.w);
            *(ushort4*)(&Ech[sr * 264 + 4 * k4]) = u;
        }
        __syncthreads();

        f32x4 sacc0 = (f32x4){0.f,0.f,0.f,0.f};
        f32x4 sacc1 = (f32x4){0.f,0.f,0.f,0.f};
        #pragma unroll
        for (int kt = 0; kt < 8; ++kt) {
            bf16x8 Bf0 = *(const bf16x8*)(&Ech[(0 * 16 + lr) * 264 + kt * 32 + lg * 8]);
            bf16x8 Bf1 = *(const bf16x8*)(&Ech[(1 * 16 + lr) * 264 + kt * 32 + lg * 8]);
            sacc0 = __builtin_amdgcn_mfma_f32_16x16x32_bf16(Ahi[kt], Bf0, sacc0, 0, 0, 0);
            sacc0 = __builtin_amdgcn_mfma_f32_16x16x32_bf16(Alo[kt], Bf0, sacc0, 0, 0, 0);
            sacc1 = __builtin_amdgcn_mfma_f32_16x16x32_bf16(Ahi[kt], Bf1, sacc1, 0, 0, 0);
            sacc1 = __builtin_amdgcn_mfma_f32_16x16x32_bf16(Alo[kt], Bf1, sacc1, 0, 0, 0);
        }

        #pragma unroll
        for (int m = 0; m < 8; ++m) {
            int idx = m * 256 + tid;
            int s = idx & 31, kq = idx >> 5;
            ushort4 v = *(const ushort4*)(&Ech[s * 264 + 4 * kq]);
            EchT[(4 * kq + 0) * 40 + s] = v.x;
            EchT[(4 * kq + 1) * 40 + s] = v.y;
            EchT[(4 * kq + 2) * 40 + s] = v.z;
            EchT[(4 * kq + 3) * 40 + s] = v.w;
        }

        float cmax[4], p0[4], p1[4], csum[4], mnew[4], scale[4];
        #pragma unroll
        for (int g = 0; g < 4; ++g) cmax[g] = fmaxf(sacc0[g], sacc1[g]);
        #pragma unroll
        for (int d = 1; d < 16; d <<= 1) {
            #pragma unroll
            for (int g = 0; g < 4; ++g) cmax[g] = fmaxf(cmax[g], __shfl_xor(cmax[g], d));
        }
        #pragma unroll
        for (int g = 0; g < 4; ++g) {
            mnew[g]  = fmaxf(mrow[g], cmax[g]);
            scale[g] = __expf(mrow[g] - mnew[g]);
            p0[g] = __expf(sacc0[g] - mnew[g]);
            p1[g] = __expf(sacc1[g] - mnew[g]);
            csum[g] = p0[g] + p1[g];
        }
        #pragma unroll
        for (int d = 1; d < 16; d <<= 1) {
            #pragma unroll
            for (int g = 0; g < 4; ++g) csum[g] += __shfl_xor(csum[g], d);
        }
        #pragma unroll
        for (int g = 0; g < 4; ++g) {
            srow[g] = srow[g] * scale[g] + csum[g];
            mrow[g] = mnew[g];
        }
        #pragma unroll
        for (int i = 0; i < 16; ++i) {
            ctx[i][0] *= scale[0]; ctx[i][1] *= scale[1];
            ctx[i][2] *= scale[2]; ctx[i][3] *= scale[3];
        }
        #pragma unroll
        for (int g = 0; g < 4; ++g) {
            int rrw = (lg * 4 + g) * 40;
            ushort h0v = f2bf(p0[g]);
            Phi[w][rrw + lr]      = h0v;
            Plo[w][rrw + lr]      = f2bf(p0[g] - bf2f(h0v));
            ushort h1v = f2bf(p1[g]);
            Phi[w][rrw + 16 + lr] = h1v;
            Plo[w][rrw + 16 + lr] = f2bf(p1[g] - bf2f(h1v));
        }
        __syncthreads();

        {
            bf16x8 Ap = *(const bf16x8*)(&Phi[w][lr * 40 + lg * 8]);
            bf16x8 Aq = *(const bf16x8*)(&Plo[w][lr * 40 + lg * 8]);
            #pragma unroll
            for (int dt = 0; dt < 16; ++dt) {
                bf16x8 Bf = *(const bf16x8*)(&EchT[(dt * 16 + lr) * 40 + lg * 8]);
                ctx[dt] = __builtin_amdgcn_mfma_f32_16x16x32_bf16(Ap, Bf, ctx[dt], 0, 0, 0);
                ctx[dt] = __builtin_amdgcn_mfma_f32_16x16x32_bf16(Aq, Bf, ctx[dt], 0, 0, 0);
            }
        }
        __syncthreads();
    }

    float inv[4];
    #pragma unroll
    for (int g = 0; g < 4; ++g) inv[g] = 1.f / srow[g];
    #pragma unroll
    for (int dt = 0; dt < 16; ++dt) {
        #pragma unroll
        for (int g = 0; g < 4; ++g) {
            out[((size_t)b * T_ + (t0 + w * 16 + lg * 4 + g)) * 512 + 256 + dt * 16 + lr] =
                ctx[dt][g] * inv[g];
        }
    }
}

// -------------------- launch --------------------

extern "C" void kernel_launch(void* const* d_in, const int* in_sizes, int n_in,
                              void* d_out, int out_size, void* d_ws, size_t ws_size,
                              hipStream_t stream)
{
    const float* de  = (const float*)d_in[0];
    const float* h0  = (const float*)d_in[1];
    const float* c0  = (const float*)d_in[2];
    const float* E   = (const float*)d_in[3];
    const float* Wih = (const float*)d_in[4];
    const float* Whh = (const float*)d_in[5];
    const float* bih = (const float*)d_in[6];
    const float* bhh = (const float*)d_in[7];
    float* out  = (float*)d_out;
    uint32_t* hbuf = (uint32_t*)d_ws;

    ws_init<<<128, 256, 0, stream>>>(hbuf);

    void* args[] = {(void*)&de, (void*)&h0, (void*)&c0, (void*)&Wih, (void*)&Whh,
                    (void*)&bih, (void*)&bhh, (void*)&out, (void*)&hbuf};
    hipLaunchCooperativeKernel((const void*)lstm_persistent,
                               dim3(GROUPS * BPG), dim3(256), args, 0, stream);

    attn_kernel<<<dim3(512), 256, 0, stream>>>(E, out);
}

// Round 7
// 1019.494 us; speedup vs baseline: 3.7250x; 1.1642x over previous
//
#include <hip/hip_runtime.h>
#include <cstdint>
#include <cstddef>

#define B_  64
#define T_  512
#define S_  512
#define D_  256

#define GROUPS 16
#define BPG    16

typedef __attribute__((ext_vector_type(4))) float f32x4;
typedef __attribute__((ext_vector_type(8))) short bf16x8;

union UBF { bf16x8 v; uint32_t u[4]; };
union USH { bf16x8 v; ushort s[8]; };

// ---- helpers ----
__device__ __forceinline__ ushort f2bf(float f) {
    union { float f; uint32_t u; } v; v.f = f;
    uint32_t r = v.u + 0x7FFFu + ((v.u >> 16) & 1u);
    return (ushort)(r >> 16);
}
__device__ __forceinline__ float bf2f(ushort h) {
    union { uint32_t u; float f; } v; v.u = ((uint32_t)h) << 16; return v.f;
}
__device__ __forceinline__ uint4 ldx4u_cg(const uint32_t* p) {
    uint4 r;
    asm volatile("global_load_dwordx4 %0, %1, off sc0 sc1\n\ts_waitcnt vmcnt(0)"
                 : "=v"(r) : "v"(p) : "memory");
    return r;
}
__device__ __forceinline__ void st_cg_u32(uint32_t* p, uint32_t v) {
    asm volatile("global_store_dword %0, %1, off sc0 sc1" :: "v"(p), "v"(v) : "memory");
}
// out = [hi16(b) : hi16(a)]  (a = even k, b = odd k)
__device__ __forceinline__ uint32_t hi2(uint32_t a, uint32_t b) {
#if __has_builtin(__builtin_amdgcn_perm)
    return __builtin_amdgcn_perm(b, a, 0x07060302u);
#else
    return (a >> 16) | (b & 0xFFFF0000u);
#endif
}

// hbuf ring: 2 slots x 16384 u32 ([slot][b][d]); word = bf16(h)<<16 | step
// init 0xFFFFFFFF (step field 0xFFFF never matches t <= 510)
__global__ __launch_bounds__(256) void ws_init(uint32_t* __restrict__ hbuf) {
    int i = blockIdx.x * 256 + threadIdx.x;
    if (i < 2 * 16384)
        __hip_atomic_store(hbuf + i, 0xFFFFFFFFu, __ATOMIC_RELAXED, __HIP_MEMORY_SCOPE_AGENT);
}

// ==================== LSTM: MFMA, counter-stamped bf16 exchange ====================
// 256 blocks x 256 threads. block = (grp, jb). wave w = gate w, 16 gate-rows.
// A-frags (Wc hi/lo) in registers. B built from wire format with 1 v_perm per u32.

__global__ __launch_bounds__(256, 1) void lstm_persistent(
    const float* __restrict__ de,  const float* __restrict__ h0,
    const float* __restrict__ c0,
    const float* __restrict__ Wih, const float* __restrict__ Whh,
    const float* __restrict__ bih, const float* __restrict__ bhh,
    float* __restrict__ out, uint32_t* __restrict__ hbuf)
{
    __shared__ uint32_t hlds[4 * 260];     // packed h, [b][d] stride 260 (2-way free)
    __shared__ float    glds[256];         // gates [gate][dlc][b]
    __shared__ float    t0buf[2][4][256];  // e0, h0

    const int tid = threadIdx.x;
    const int grp = blockIdx.x >> 4;
    const int jb  = blockIdx.x & 15;

    const int w  = tid >> 6;    // wave = gate
    const int l  = tid & 63;
    const int lr = l & 15;      // A row (dlc) / acc col (batch if <4)
    const int lg = l >> 4;

    const int cb  = tid & 3;    // combine mapping (tid < 64)
    const int cd  = tid >> 2;
    const int bx  = grp * 4 + cb;
    const int dxc = jb * 16 + cd;

    float c_reg = 0.f;
    float bsum0 = 0.f, bsum1 = 0.f, bsum2 = 0.f, bsum3 = 0.f;
    if (tid < 64) {
        c_reg = c0[(size_t)bx * 256 + dxc];
        bsum0 = bih[      jb * 16 + cd] + bhh[      jb * 16 + cd];
        bsum1 = bih[256 + jb * 16 + cd] + bhh[256 + jb * 16 + cd];
        bsum2 = bih[512 + jb * 16 + cd] + bhh[512 + jb * 16 + cd];
        bsum3 = bih[768 + jb * 16 + cd] + bhh[768 + jb * 16 + cd];
    }

    bf16x8 Ahi[8], Alo[8];

    // ---- t = 0: stage e0/h0, scalar dot into glds ----
    #pragma unroll
    for (int m = 0; m < 8; ++m) {
        int idx = m * 256 + tid;
        int arr = idx >> 10, bl = (idx >> 8) & 3, k = idx & 255;
        t0buf[arr][bl][k] = arr ? h0[(size_t)(grp * 4 + bl) * 256 + k]
                                : de[(size_t)(grp * 4 + bl) * T_ * D_ + k];
    }
    __syncthreads();
    {
        int r = tid >> 2, bq = tid & 3;
        int gr = (r >> 4) * 256 + jb * 16 + (r & 15);
        const float4* wi4 = (const float4*)(Wih + (size_t)gr * 256);
        const float4* wh4 = (const float4*)(Whh + (size_t)gr * 256);
        const float4* e4  = (const float4*)(&t0buf[0][bq][0]);
        const float4* h4  = (const float4*)(&t0buf[1][bq][0]);
        float a0 = 0.f, a1 = 0.f, a2 = 0.f, a3 = 0.f;
        #pragma unroll 8
        for (int k4 = 0; k4 < 64; ++k4) {
            float4 x = wi4[k4], y = e4[k4];
            a0 += x.x*y.x; a1 += x.y*y.y; a2 += x.z*y.z; a3 += x.w*y.w;
            x = wh4[k4]; y = h4[k4];
            a0 += x.x*y.x; a1 += x.y*y.y; a2 += x.z*y.z; a3 += x.w*y.w;
        }
        glds[(r >> 4) * 64 + (r & 15) * 4 + bq] = (a0 + a1) + (a2 + a3);
    }

    for (int t = 0; t < T_; ++t) {
        if (t > 0) {
            // ---- poll h_{t-1}: 16-bit step counter is the flag ----
            const uint32_t expc = (uint32_t)(t - 1);
            const uint32_t* hp = hbuf + ((t - 1) & 1) * 16384 + grp * 1024 + tid * 4;
            uint4 v = ldx4u_cg(hp);
            while ((((v.x ^ expc) | (v.y ^ expc) | (v.z ^ expc) | (v.w ^ expc)) & 0xFFFFu) != 0u)
                v = ldx4u_cg(hp);
            *(uint4*)(hlds + (tid >> 6) * 260 + (tid & 63) * 4) = v;
            __syncthreads();

            // ---- B-frags via v_perm + dual-acc MFMA ----
            f32x4 acch = (f32x4){0.f, 0.f, 0.f, 0.f};
            f32x4 accl = (f32x4){0.f, 0.f, 0.f, 0.f};
            const uint32_t* hrow = hlds + (lr & 3) * 260 + lg * 8;
            #pragma unroll
            for (int kt = 0; kt < 8; ++kt) {
                uint4 q0 = *(const uint4*)(hrow + kt * 32);
                uint4 q1 = *(const uint4*)(hrow + kt * 32 + 4);
                UBF bb;
                bb.u[0] = hi2(q0.x, q0.y);
                bb.u[1] = hi2(q0.z, q0.w);
                bb.u[2] = hi2(q1.x, q1.y);
                bb.u[3] = hi2(q1.z, q1.w);
                acch = __builtin_amdgcn_mfma_f32_16x16x32_bf16(Ahi[kt], bb.v, acch, 0, 0, 0);
                accl = __builtin_amdgcn_mfma_f32_16x16x32_bf16(Alo[kt], bb.v, accl, 0, 0, 0);
            }
            f32x4 acc = acch + accl;
            if (lr < 4) {
                glds[w * 64 + (lg * 4 + 0) * 4 + lr] = acc[0];
                glds[w * 64 + (lg * 4 + 1) * 4 + lr] = acc[1];
                glds[w * 64 + (lg * 4 + 2) * 4 + lr] = acc[2];
                glds[w * 64 + (lg * 4 + 3) * 4 + lr] = acc[3];
            }
        }
        __syncthreads();

        // ---- combine: gate math, store packed h first, then out ----
        if (tid < 64) {
            float gi = glds[      cd * 4 + cb] + bsum0;
            float gf = glds[ 64 + cd * 4 + cb] + bsum1;
            float gg = glds[128 + cd * 4 + cb] + bsum2;
            float go = glds[192 + cd * 4 + cb] + bsum3;
            float si = 1.f / (1.f + __expf(-gi));
            float sf = 1.f / (1.f + __expf(-gf));
            float so = 1.f / (1.f + __expf(-go));
            float tg = 1.f - 2.f / (1.f + __expf(2.f * gg));
            c_reg = sf * c_reg + si * tg;
            float tc = 1.f - 2.f / (1.f + __expf(2.f * c_reg));
            float hn = so * tc;
            if (t < T_ - 1) {
                uint32_t pk = ((uint32_t)f2bf(hn) << 16) | (uint32_t)t;
                st_cg_u32(hbuf + (t & 1) * 16384 + grp * 1024 + cb * 256 + dxc, pk);
            }
            out[((size_t)bx * T_ + t) * 512 + dxc] = hn;
        }

        if (t == 0) {
            // ---- one-time: build Wc hi/lo A-frags ----
            int gr = w * 256 + jb * 16 + lr;
            const float4* wi4 = (const float4*)(Wih + (size_t)gr * 256);
            const float4* wh4 = (const float4*)(Whh + (size_t)gr * 256);
            #pragma unroll
            for (int kt = 0; kt < 8; ++kt) {
                float4 p  = wi4[kt * 8 + lg * 2], q  = wi4[kt * 8 + lg * 2 + 1];
                float4 r4 = wh4[kt * 8 + lg * 2], s4 = wh4[kt * 8 + lg * 2 + 1];
                float f[8] = {p.x + r4.x, p.y + r4.y, p.z + r4.z, p.w + r4.w,
                              q.x + s4.x, q.y + s4.y, q.z + s4.z, q.w + s4.w};
                USH hi, lo;
                #pragma unroll
                for (int j = 0; j < 8; ++j) {
                    ushort h = f2bf(f[j]);
                    hi.s[j] = h;
                    lo.s[j] = f2bf(f[j] - bf2f(h));
                }
                Ahi[kt] = hi.v; Alo[kt] = lo.v;
            }
        }
    }
}

// ==================== Attention: bf16 MFMA flash (unchanged, verified) ========

__global__ __launch_bounds__(256, 2) void attn_kernel(
    const float* __restrict__ E, float* __restrict__ out)
{
    __shared__ alignas(16) ushort Ech [32 * 264];
    __shared__ alignas(16) ushort EchT[256 * 40];
    __shared__ alignas(16) ushort Phi[4][16 * 40];
    __shared__ alignas(16) ushort Plo[4][16 * 40];

    const int id  = blockIdx.x;
    const int xcd = id & 7, rr = id >> 3;
    const int tt  = rr & 7,  bh = rr >> 3;
    const int b   = bh * 8 + xcd;
    const int t0  = tt * 64;

    const int tid = threadIdx.x;
    const int w   = tid >> 6;
    const int l   = tid & 63;
    const int lr  = l & 15;
    const int lg  = l >> 4;

    bf16x8 Ahi[8], Alo[8];
    {
        const float* Hrow = out + ((size_t)b * T_ + (t0 + w * 16 + lr)) * 512;
        #pragma unroll
        for (int kt = 0; kt < 8; ++kt) {
            float4 x0 = *(const float4*)(Hrow + kt * 32 + lg * 8);
            float4 x1 = *(const float4*)(Hrow + kt * 32 + lg * 8 + 4);
            float f[8] = {x0.x, x0.y, x0.z, x0.w, x1.x, x1.y, x1.z, x1.w};
            USH hi, lo;
            #pragma unroll
            for (int j = 0; j < 8; ++j) {
                ushort h = f2bf(f[j]);
                hi.s[j] = h;
                lo.s[j] = f2bf(f[j] - bf2f(h));
            }
            Ahi[kt] = hi.v; Alo[kt] = lo.v;
        }
    }

    f32x4 ctx[16];
    #pragma unroll
    for (int i = 0; i < 16; ++i) ctx[i] = (f32x4){0.f, 0.f, 0.f, 0.f};
    float mrow[4] = {-1e30f, -1e30f, -1e30f, -1e30f};
    float srow[4] = {0.f, 0.f, 0.f, 0.f};

    const float* Eb = E + (size_t)b * S_ * 256;

    for (int c = 0; c < 16; ++c) {
        #pragma unroll
        for (int m = 0; m < 8; ++m) {
            int idx = m * 256 + tid;
            int sr = idx >> 6, k4 = idx & 63;
            float4 e = *(const float4*)(Eb + (size_t)(c * 32 + sr) * 256 + 4 * k4);
            ushort4 u;
            u.x = f2bf(e.x); u.y = f2bf(e.y); u.z = f2bf(e.z); u.w = f2bf(e.w);
            *(ushort4*)(&Ech[sr * 264 + 4 * k4]) = u;
        }
        __syncthreads();

        f32x4 sacc0 = (f32x4){0.f,0.f,0.f,0.f};
        f32x4 sacc1 = (f32x4){0.f,0.f,0.f,0.f};
        #pragma unroll
        for (int kt = 0; kt < 8; ++kt) {
            bf16x8 Bf0 = *(const bf16x8*)(&Ech[(0 * 16 + lr) * 264 + kt * 32 + lg * 8]);
            bf16x8 Bf1 = *(const bf16x8*)(&Ech[(1 * 16 + lr) * 264 + kt * 32 + lg * 8]);
            sacc0 = __builtin_amdgcn_mfma_f32_16x16x32_bf16(Ahi[kt], Bf0, sacc0, 0, 0, 0);
            sacc0 = __builtin_amdgcn_mfma_f32_16x16x32_bf16(Alo[kt], Bf0, sacc0, 0, 0, 0);
            sacc1 = __builtin_amdgcn_mfma_f32_16x16x32_bf16(Ahi[kt], Bf1, sacc1, 0, 0, 0);
            sacc1 = __builtin_amdgcn_mfma_f32_16x16x32_bf16(Alo[kt], Bf1, sacc1, 0, 0, 0);
        }

        #pragma unroll
        for (int m = 0; m < 8; ++m) {
            int idx = m * 256 + tid;
            int s = idx & 31, kq = idx >> 5;
            ushort4 v = *(const ushort4*)(&Ech[s * 264 + 4 * kq]);
            EchT[(4 * kq + 0) * 40 + s] = v.x;
            EchT[(4 * kq + 1) * 40 + s] = v.y;
            EchT[(4 * kq + 2) * 40 + s] = v.z;
            EchT[(4 * kq + 3) * 40 + s] = v.w;
        }

        float cmax[4], p0[4], p1[4], csum[4], mnew[4], scale[4];
        #pragma unroll
        for (int g = 0; g < 4; ++g) cmax[g] = fmaxf(sacc0[g], sacc1[g]);
        #pragma unroll
        for (int d = 1; d < 16; d <<= 1) {
            #pragma unroll
            for (int g = 0; g < 4; ++g) cmax[g] = fmaxf(cmax[g], __shfl_xor(cmax[g], d));
        }
        #pragma unroll
        for (int g = 0; g < 4; ++g) {
            mnew[g]  = fmaxf(mrow[g], cmax[g]);
            scale[g] = __expf(mrow[g] - mnew[g]);
            p0[g] = __expf(sacc0[g] - mnew[g]);
            p1[g] = __expf(sacc1[g] - mnew[g]);
            csum[g] = p0[g] + p1[g];
        }
        #pragma unroll
        for (int d = 1; d < 16; d <<= 1) {
            #pragma unroll
            for (int g = 0; g < 4; ++g) csum[g] += __shfl_xor(csum[g], d);
        }
        #pragma unroll
        for (int g = 0; g < 4; ++g) {
            srow[g] = srow[g] * scale[g] + csum[g];
            mrow[g] = mnew[g];
        }
        #pragma unroll
        for (int i = 0; i < 16; ++i) {
            ctx[i][0] *= scale[0]; ctx[i][1] *= scale[1];
            ctx[i][2] *= scale[2]; ctx[i][3] *= scale[3];
        }
        #pragma unroll
        for (int g = 0; g < 4; ++g) {
            int rrw = (lg * 4 + g) * 40;
            ushort h0v = f2bf(p0[g]);
            Phi[w][rrw + lr]      = h0v;
            Plo[w][rrw + lr]      = f2bf(p0[g] - bf2f(h0v));
            ushort h1v = f2bf(p1[g]);
            Phi[w][rrw + 16 + lr] = h1v;
            Plo[w][rrw + 16 + lr] = f2bf(p1[g] - bf2f(h1v));
        }
        __syncthreads();

        {
            bf16x8 Ap = *(const bf16x8*)(&Phi[w][lr * 40 + lg * 8]);
            bf16x8 Aq = *(const bf16x8*)(&Plo[w][lr * 40 + lg * 8]);
            #pragma unroll
            for (int dt = 0; dt < 16; ++dt) {
                bf16x8 Bf = *(const bf16x8*)(&EchT[(dt * 16 + lr) * 40 + lg * 8]);
                ctx[dt] = __builtin_amdgcn_mfma_f32_16x16x32_bf16(Ap, Bf, ctx[dt], 0, 0, 0);
                ctx[dt] = __builtin_amdgcn_mfma_f32_16x16x32_bf16(Aq, Bf, ctx[dt], 0, 0, 0);
            }
        }
        __syncthreads();
    }

    float inv[4];
    #pragma unroll
    for (int g = 0; g < 4; ++g) inv[g] = 1.f / srow[g];
    #pragma unroll
    for (int dt = 0; dt < 16; ++dt) {
        #pragma unroll
        for (int g = 0; g < 4; ++g) {
            out[((size_t)b * T_ + (t0 + w * 16 + lg * 4 + g)) * 512 + 256 + dt * 16 + lr] =
                ctx[dt][g] * inv[g];
        }
    }
}

// -------------------- launch --------------------

extern "C" void kernel_launch(void* const* d_in, const int* in_sizes, int n_in,
                              void* d_out, int out_size, void* d_ws, size_t ws_size,
                              hipStream_t stream)
{
    const float* de  = (const float*)d_in[0];
    const float* h0  = (const float*)d_in[1];
    const float* c0  = (const float*)d_in[2];
    const float* E   = (const float*)d_in[3];
    const float* Wih = (const float*)d_in[4];
    const float* Whh = (const float*)d_in[5];
    const float* bih = (const float*)d_in[6];
    const float* bhh = (const float*)d_in[7];
    float* out  = (float*)d_out;
    uint32_t* hbuf = (uint32_t*)d_ws;

    ws_init<<<128, 256, 0, stream>>>(hbuf);

    void* args[] = {(void*)&de, (void*)&h0, (void*)&c0, (void*)&Wih, (void*)&Whh,
                    (void*)&bih, (void*)&bhh, (void*)&out, (void*)&hbuf};
    hipLaunchCooperativeKernel((const void*)lstm_persistent,
                               dim3(GROUPS * BPG), dim3(256), args, 0, stream);

    attn_kernel<<<dim3(512), 256, 0, stream>>>(E, out);
}

// Round 10
// 1019.044 us; speedup vs baseline: 3.7267x; 1.0004x over previous
//
#include <hip/hip_runtime.h>
#include <cstdint>
#include <cstddef>

#define B_  64
#define T_  512
#define S_  512
#define D_  256

#define GROUPS 16
#define BPG    16

typedef __attribute__((ext_vector_type(4))) float f32x4;
typedef __attribute__((ext_vector_type(8))) short bf16x8;

union UBF { bf16x8 v; uint32_t u[4]; };
union USH { bf16x8 v; ushort s[8]; };

// ---- helpers ----
__device__ __forceinline__ ushort f2bf(float f) {
    union { float f; uint32_t u; } v; v.f = f;
    uint32_t r = v.u + 0x7FFFu + ((v.u >> 16) & 1u);
    return (ushort)(r >> 16);
}
__device__ __forceinline__ float bf2f(ushort h) {
    union { uint32_t u; float f; } v; v.u = ((uint32_t)h) << 16; return v.f;
}
__device__ __forceinline__ uint4 ldx4u_cg(const uint32_t* p) {
    uint4 r;
    asm volatile("global_load_dwordx4 %0, %1, off sc0 sc1\n\ts_waitcnt vmcnt(0)"
                 : "=v"(r) : "v"(p) : "memory");
    return r;
}
__device__ __forceinline__ void st_cg_u32(uint32_t* p, uint32_t v) {
    asm volatile("global_store_dword %0, %1, off sc0 sc1" :: "v"(p), "v"(v) : "memory");
}
// out = [hi16(b) : hi16(a)]  (a = even k, b = odd k)
__device__ __forceinline__ uint32_t hi2(uint32_t a, uint32_t b) {
#if __has_builtin(__builtin_amdgcn_perm)
    return __builtin_amdgcn_perm(b, a, 0x07060302u);
#else
    return (a >> 16) | (b & 0xFFFF0000u);
#endif
}

// hbuf ring: 2 slots x 16384 u32 ([slot][b][d]); word = bf16(h)<<16 | step
// init 0xFFFFFFFF (step field 0xFFFF never matches t <= 510)
__global__ __launch_bounds__(256) void ws_init(uint32_t* __restrict__ hbuf) {
    int i = blockIdx.x * 256 + threadIdx.x;
    if (i < 2 * 16384)
        __hip_atomic_store(hbuf + i, 0xFFFFFFFFu, __ATOMIC_RELAXED, __HIP_MEMORY_SCOPE_AGENT);
}

// ==================== LSTM: MFMA, counter-stamped bf16 exchange ====================
// 256 blocks x 256 threads. block = (grp, jb). wave w = gate w, 16 gate-rows.
// A-frags (Wc hi/lo) in registers. B built from wire format with 1 v_perm per u32.
// This is the verified R7 configuration (passed at lstm=913us, absmax 0.0156).

__global__ __launch_bounds__(256, 1) void lstm_persistent(
    const float* __restrict__ de,  const float* __restrict__ h0,
    const float* __restrict__ c0,
    const float* __restrict__ Wih, const float* __restrict__ Whh,
    const float* __restrict__ bih, const float* __restrict__ bhh,
    float* __restrict__ out, uint32_t* __restrict__ hbuf)
{
    __shared__ uint32_t hlds[4 * 260];     // packed h, [b][d] stride 260
    __shared__ float    glds[256];         // gates [gate][dlc][b]
    __shared__ float    t0buf[2][4][256];  // e0, h0

    const int tid = threadIdx.x;
    const int grp = blockIdx.x >> 4;
    const int jb  = blockIdx.x & 15;

    const int w  = tid >> 6;    // wave = gate
    const int l  = tid & 63;
    const int lr = l & 15;      // A row (dlc) / acc col (batch if <4)
    const int lg = l >> 4;

    const int cb  = tid & 3;    // combine mapping (tid < 64)
    const int cd  = tid >> 2;
    const int bx  = grp * 4 + cb;
    const int dxc = jb * 16 + cd;

    float c_reg = 0.f;
    float bsum0 = 0.f, bsum1 = 0.f, bsum2 = 0.f, bsum3 = 0.f;
    if (tid < 64) {
        c_reg = c0[(size_t)bx * 256 + dxc];
        bsum0 = bih[      jb * 16 + cd] + bhh[      jb * 16 + cd];
        bsum1 = bih[256 + jb * 16 + cd] + bhh[256 + jb * 16 + cd];
        bsum2 = bih[512 + jb * 16 + cd] + bhh[512 + jb * 16 + cd];
        bsum3 = bih[768 + jb * 16 + cd] + bhh[768 + jb * 16 + cd];
    }

    bf16x8 Ahi[8], Alo[8];

    // ---- t = 0: stage e0/h0, scalar dot into glds ----
    #pragma unroll
    for (int m = 0; m < 8; ++m) {
        int idx = m * 256 + tid;
        int arr = idx >> 10, bl = (idx >> 8) & 3, k = idx & 255;
        t0buf[arr][bl][k] = arr ? h0[(size_t)(grp * 4 + bl) * 256 + k]
                                : de[(size_t)(grp * 4 + bl) * T_ * D_ + k];
    }
    __syncthreads();
    {
        int r = tid >> 2, bq = tid & 3;
        int gr = (r >> 4) * 256 + jb * 16 + (r & 15);
        const float4* wi4 = (const float4*)(Wih + (size_t)gr * 256);
        const float4* wh4 = (const float4*)(Whh + (size_t)gr * 256);
        const float4* e4  = (const float4*)(&t0buf[0][bq][0]);
        const float4* h4  = (const float4*)(&t0buf[1][bq][0]);
        float a0 = 0.f, a1 = 0.f, a2 = 0.f, a3 = 0.f;
        #pragma unroll 8
        for (int k4 = 0; k4 < 64; ++k4) {
            float4 x = wi4[k4], y = e4[k4];
            a0 += x.x*y.x; a1 += x.y*y.y; a2 += x.z*y.z; a3 += x.w*y.w;
            x = wh4[k4]; y = h4[k4];
            a0 += x.x*y.x; a1 += x.y*y.y; a2 += x.z*y.z; a3 += x.w*y.w;
        }
        glds[(r >> 4) * 64 + (r & 15) * 4 + bq] = (a0 + a1) + (a2 + a3);
    }

    for (int t = 0; t < T_; ++t) {
        if (t > 0) {
            // ---- poll h_{t-1}: 16-bit step counter is the flag ----
            const uint32_t expc = (uint32_t)(t - 1);
            const uint32_t* hp = hbuf + ((t - 1) & 1) * 16384 + grp * 1024 + tid * 4;
            uint4 v = ldx4u_cg(hp);
            while ((((v.x ^ expc) | (v.y ^ expc) | (v.z ^ expc) | (v.w ^ expc)) & 0xFFFFu) != 0u)
                v = ldx4u_cg(hp);
            *(uint4*)(hlds + (tid >> 6) * 260 + (tid & 63) * 4) = v;
            __syncthreads();

            // ---- B-frags via v_perm + dual-acc MFMA ----
            f32x4 acch = (f32x4){0.f, 0.f, 0.f, 0.f};
            f32x4 accl = (f32x4){0.f, 0.f, 0.f, 0.f};
            const uint32_t* hrow = hlds + (lr & 3) * 260 + lg * 8;
            #pragma unroll
            for (int kt = 0; kt < 8; ++kt) {
                uint4 q0 = *(const uint4*)(hrow + kt * 32);
                uint4 q1 = *(const uint4*)(hrow + kt * 32 + 4);
                UBF bb;
                bb.u[0] = hi2(q0.x, q0.y);
                bb.u[1] = hi2(q0.z, q0.w);
                bb.u[2] = hi2(q1.x, q1.y);
                bb.u[3] = hi2(q1.z, q1.w);
                acch = __builtin_amdgcn_mfma_f32_16x16x32_bf16(Ahi[kt], bb.v, acch, 0, 0, 0);
                accl = __builtin_amdgcn_mfma_f32_16x16x32_bf16(Alo[kt], bb.v, accl, 0, 0, 0);
            }
            f32x4 acc = acch + accl;
            if (lr < 4) {
                glds[w * 64 + (lg * 4 + 0) * 4 + lr] = acc[0];
                glds[w * 64 + (lg * 4 + 1) * 4 + lr] = acc[1];
                glds[w * 64 + (lg * 4 + 2) * 4 + lr] = acc[2];
                glds[w * 64 + (lg * 4 + 3) * 4 + lr] = acc[3];
            }
        }
        __syncthreads();

        // ---- combine: gate math, store packed h first, then out ----
        if (tid < 64) {
            float gi = glds[      cd * 4 + cb] + bsum0;
            float gf = glds[ 64 + cd * 4 + cb] + bsum1;
            float gg = glds[128 + cd * 4 + cb] + bsum2;
            float go = glds[192 + cd * 4 + cb] + bsum3;
            float si = 1.f / (1.f + __expf(-gi));
            float sf = 1.f / (1.f + __expf(-gf));
            float so = 1.f / (1.f + __expf(-go));
            float tg = 1.f - 2.f / (1.f + __expf(2.f * gg));
            c_reg = sf * c_reg + si * tg;
            float tc = 1.f - 2.f / (1.f + __expf(2.f * c_reg));
            float hn = so * tc;
            if (t < T_ - 1) {
                uint32_t pk = ((uint32_t)f2bf(hn) << 16) | (uint32_t)t;
                st_cg_u32(hbuf + (t & 1) * 16384 + grp * 1024 + cb * 256 + dxc, pk);
            }
            out[((size_t)bx * T_ + t) * 512 + dxc] = hn;
        }

        if (t == 0) {
            // ---- one-time: build Wc hi/lo A-frags ----
            int gr = w * 256 + jb * 16 + lr;
            const float4* wi4 = (const float4*)(Wih + (size_t)gr * 256);
            const float4* wh4 = (const float4*)(Whh + (size_t)gr * 256);
            #pragma unroll
            for (int kt = 0; kt < 8; ++kt) {
                float4 p  = wi4[kt * 8 + lg * 2], q  = wi4[kt * 8 + lg * 2 + 1];
                float4 r4 = wh4[kt * 8 + lg * 2], s4 = wh4[kt * 8 + lg * 2 + 1];
                float f[8] = {p.x + r4.x, p.y + r4.y, p.z + r4.z, p.w + r4.w,
                              q.x + s4.x, q.y + s4.y, q.z + s4.z, q.w + s4.w};
                USH hi, lo;
                #pragma unroll
                for (int j = 0; j < 8; ++j) {
                    ushort h = f2bf(f[j]);
                    hi.s[j] = h;
                    lo.s[j] = f2bf(f[j] - bf2f(h));
                }
                Ahi[kt] = hi.v; Alo[kt] = lo.v;
            }
        }
    }
}

// ==================== Attention: bf16 MFMA flash (unchanged, verified) ========

__global__ __launch_bounds__(256, 2) void attn_kernel(
    const float* __restrict__ E, float* __restrict__ out)
{
    __shared__ alignas(16) ushort Ech [32 * 264];
    __shared__ alignas(16) ushort EchT[256 * 40];
    __shared__ alignas(16) ushort Phi[4][16 * 40];
    __shared__ alignas(16) ushort Plo[4][16 * 40];

    const int id  = blockIdx.x;
    const int xcd = id & 7, rr = id >> 3;
    const int tt  = rr & 7,  bh = rr >> 3;
    const int b   = bh * 8 + xcd;
    const int t0  = tt * 64;

    const int tid = threadIdx.x;
    const int w   = tid >> 6;
    const int l   = tid & 63;
    const int lr  = l & 15;
    const int lg  = l >> 4;

    bf16x8 Ahi[8], Alo[8];
    {
        const float* Hrow = out + ((size_t)b * T_ + (t0 + w * 16 + lr)) * 512;
        #pragma unroll
        for (int kt = 0; kt < 8; ++kt) {
            float4 x0 = *(const float4*)(Hrow + kt * 32 + lg * 8);
            float4 x1 = *(const float4*)(Hrow + kt * 32 + lg * 8 + 4);
            float f[8] = {x0.x, x0.y, x0.z, x0.w, x1.x, x1.y, x1.z, x1.w};
            USH hi, lo;
            #pragma unroll
            for (int j = 0; j < 8; ++j) {
                ushort h = f2bf(f[j]);
                hi.s[j] = h;
                lo.s[j] = f2bf(f[j] - bf2f(h));
            }
            Ahi[kt] = hi.v; Alo[kt] = lo.v;
        }
    }

    f32x4 ctx[16];
    #pragma unroll
    for (int i = 0; i < 16; ++i) ctx[i] = (f32x4){0.f, 0.f, 0.f, 0.f};
    float mrow[4] = {-1e30f, -1e30f, -1e30f, -1e30f};
    float srow[4] = {0.f, 0.f, 0.f, 0.f};

    const float* Eb = E + (size_t)b * S_ * 256;

    for (int c = 0; c < 16; ++c) {
        #pragma unroll
        for (int m = 0; m < 8; ++m) {
            int idx = m * 256 + tid;
            int sr = idx >> 6, k4 = idx & 63;
            float4 e = *(const float4*)(Eb + (size_t)(c * 32 + sr) * 256 + 4 * k4);
            ushort4 u;
            u.x = f2bf(e.x); u.y = f2bf(e.y); u.z = f2bf(e.z); u.w = f2bf(e.w);
            *(ushort4*)(&Ech[sr * 264 + 4 * k4]) = u;
        }
        __syncthreads();

        f32x4 sacc0 = (f32x4){0.f,0.f,0.f,0.f};
        f32x4 sacc1 = (f32x4){0.f,0.f,0.f,0.f};
        #pragma unroll
        for (int kt = 0; kt < 8; ++kt) {
            bf16x8 Bf0 = *(const bf16x8*)(&Ech[(0 * 16 + lr) * 264 + kt * 32 + lg * 8]);
            bf16x8 Bf1 = *(const bf16x8*)(&Ech[(1 * 16 + lr) * 264 + kt * 32 + lg * 8]);
            sacc0 = __builtin_amdgcn_mfma_f32_16x16x32_bf16(Ahi[kt], Bf0, sacc0, 0, 0, 0);
            sacc0 = __builtin_amdgcn_mfma_f32_16x16x32_bf16(Alo[kt], Bf0, sacc0, 0, 0, 0);
            sacc1 = __builtin_amdgcn_mfma_f32_16x16x32_bf16(Ahi[kt], Bf1, sacc1, 0, 0, 0);
            sacc1 = __builtin_amdgcn_mfma_f32_16x16x32_bf16(Alo[kt], Bf1, sacc1, 0, 0, 0);
        }

        #pragma unroll
        for (int m = 0; m < 8; ++m) {
            int idx = m * 256 + tid;
            int s = idx & 31, kq = idx >> 5;
            ushort4 v = *(const ushort4*)(&Ech[s * 264 + 4 * kq]);
            EchT[(4 * kq + 0) * 40 + s] = v.x;
            EchT[(4 * kq + 1) * 40 + s] = v.y;
            EchT[(4 * kq + 2) * 40 + s] = v.z;
            EchT[(4 * kq + 3) * 40 + s] = v.w;
        }

        float cmax[4], p0[4], p1[4], csum[4], mnew[4], scale[4];
        #pragma unroll
        for (int g = 0; g < 4; ++g) cmax[g] = fmaxf(sacc0[g], sacc1[g]);
        #pragma unroll
        for (int d = 1; d < 16; d <<= 1) {
            #pragma unroll
            for (int g = 0; g < 4; ++g) cmax[g] = fmaxf(cmax[g], __shfl_xor(cmax[g], d));
        }
        #pragma unroll
        for (int g = 0; g < 4; ++g) {
            mnew[g]  = fmaxf(mrow[g], cmax[g]);
            scale[g] = __expf(mrow[g] - mnew[g]);
            p0[g] = __expf(sacc0[g] - mnew[g]);
            p1[g] = __expf(sacc1[g] - mnew[g]);
            csum[g] = p0[g] + p1[g];
        }
        #pragma unroll
        for (int d = 1; d < 16; d <<= 1) {
            #pragma unroll
            for (int g = 0; g < 4; ++g) csum[g] += __shfl_xor(csum[g], d);
        }
        #pragma unroll
        for (int g = 0; g < 4; ++g) {
            srow[g] = srow[g] * scale[g] + csum[g];
            mrow[g] = mnew[g];
        }
        #pragma unroll
        for (int i = 0; i < 16; ++i) {
            ctx[i][0] *= scale[0]; ctx[i][1] *= scale[1];
            ctx[i][2] *= scale[2]; ctx[i][3] *= scale[3];
        }
        #pragma unroll
        for (int g = 0; g < 4; ++g) {
            int rrw = (lg * 4 + g) * 40;
            ushort h0v = f2bf(p0[g]);
            Phi[w][rrw + lr]      = h0v;
            Plo[w][rrw + lr]      = f2bf(p0[g] - bf2f(h0v));
            ushort h1v = f2bf(p1[g]);
            Phi[w][rrw + 16 + lr] = h1v;
            Plo[w][rrw + 16 + lr] = f2bf(p1[g] - bf2f(h1v));
        }
        __syncthreads();

        {
            bf16x8 Ap = *(const bf16x8*)(&Phi[w][lr * 40 + lg * 8]);
            bf16x8 Aq = *(const bf16x8*)(&Plo[w][lr * 40 + lg * 8]);
            #pragma unroll
            for (int dt = 0; dt < 16; ++dt) {
                bf16x8 Bf = *(const bf16x8*)(&EchT[(dt * 16 + lr) * 40 + lg * 8]);
                ctx[dt] = __builtin_amdgcn_mfma_f32_16x16x32_bf16(Ap, Bf, ctx[dt], 0, 0, 0);
                ctx[dt] = __builtin_amdgcn_mfma_f32_16x16x32_bf16(Aq, Bf, ctx[dt], 0, 0, 0);
            }
        }
        __syncthreads();
    }

    float inv[4];
    #pragma unroll
    for (int g = 0; g < 4; ++g) inv[g] = 1.f / srow[g];
    #pragma unroll
    for (int dt = 0; dt < 16; ++dt) {
        #pragma unroll
        for (int g = 0; g < 4; ++g) {
            out[((size_t)b * T_ + (t0 + w * 16 + lg * 4 + g)) * 512 + 256 + dt * 16 + lr] =
                ctx[dt][g] * inv[g];
        }
    }
}

// -------------------- launch --------------------

extern "C" void kernel_launch(void* const* d_in, const int* in_sizes, int n_in,
                              void* d_out, int out_size, void* d_ws, size_t ws_size,
                              hipStream_t stream)
{
    const float* de  = (const float*)d_in[0];
    const float* h0  = (const float*)d_in[1];
    const float* c0  = (const float*)d_in[2];
    const float* E   = (const float*)d_in[3];
    const float* Wih = (const float*)d_in[4];
    const float* Whh = (const float*)d_in[5];
    const float* bih = (const float*)d_in[6];
    const float* bhh = (const float*)d_in[7];
    float* out  = (float*)d_out;
    uint32_t* hbuf = (uint32_t*)d_ws;

    ws_init<<<128, 256, 0, stream>>>(hbuf);

    void* args[] = {(void*)&de, (void*)&h0, (void*)&c0, (void*)&Wih, (void*)&Whh,
                    (void*)&bih, (void*)&bhh, (void*)&out, (void*)&hbuf};
    hipLaunchCooperativeKernel((const void*)lstm_persistent,
                               dim3(GROUPS * BPG), dim3(256), args, 0, stream);

    attn_kernel<<<dim3(512), 256, 0, stream>>>(E, out);
}

// Round 11
// 965.216 us; speedup vs baseline: 3.9345x; 1.0558x over previous
//
#include <hip/hip_runtime.h>
#include <cstdint>
#include <cstddef>

#define B_  64
#define T_  512
#define S_  512
#define D_  256

#define GROUPS 16
#define BPG    16

typedef __attribute__((ext_vector_type(4))) float f32x4;
typedef __attribute__((ext_vector_type(8))) short bf16x8;

union UBF { bf16x8 v; uint32_t u[4]; };
union USH { bf16x8 v; ushort s[8]; };

// ---- helpers ----
__device__ __forceinline__ ushort f2bf(float f) {
    union { float f; uint32_t u; } v; v.f = f;
    uint32_t r = v.u + 0x7FFFu + ((v.u >> 16) & 1u);
    return (ushort)(r >> 16);
}
__device__ __forceinline__ float bf2f(ushort h) {
    union { uint32_t u; float f; } v; v.u = ((uint32_t)h) << 16; return v.f;
}
__device__ __forceinline__ uint4 ldx4u_cg(const uint32_t* p) {
    uint4 r;
    asm volatile("global_load_dwordx4 %0, %1, off sc0 sc1\n\ts_waitcnt vmcnt(0)"
                 : "=v"(r) : "v"(p) : "memory");
    return r;
}
__device__ __forceinline__ void st_cg_u32(uint32_t* p, uint32_t v) {
    asm volatile("global_store_dword %0, %1, off sc0 sc1" :: "v"(p), "v"(v) : "memory");
}
// out = [hi16(b) : hi16(a)]  (a = even k, b = odd k)
__device__ __forceinline__ uint32_t hi2(uint32_t a, uint32_t b) {
#if __has_builtin(__builtin_amdgcn_perm)
    return __builtin_amdgcn_perm(b, a, 0x07060302u);
#else
    return (a >> 16) | (b & 0xFFFF0000u);
#endif
}

// hbuf ring: 2 slots x 16384 u32 ([slot][b][d]); word = bf16(h)<<16 | step
// init 0xFFFFFFFF (step field 0xFFFF never matches t <= 510)
__global__ __launch_bounds__(256) void ws_init(uint32_t* __restrict__ hbuf) {
    int i = blockIdx.x * 256 + threadIdx.x;
    if (i < 2 * 16384)
        __hip_atomic_store(hbuf + i, 0xFFFFFFFFu, __ATOMIC_RELAXED, __HIP_MEMORY_SCOPE_AGENT);
}

// ==================== LSTM: MFMA with IN-LANE gate combine ====================
// R7 geometry (256 blocks x 256 thr, block = (grp, jb)), R7 wire/poll/staging.
// ONLY change vs R7: A-row binding r -> (gate r&3, dim jb*16 + w*4 + (r>>2)),
// so lane (lr,lg) reg g holds gate g of (batch lr&3, dim jb*16+w*4+lg) after
// the MFMA (C/D map: row=(lane>>4)*4+reg, col=lane&15). Gate math is in-lane;
// glds hop removed from the steady state; each wave stores h right after its
// own MFMA (no cross-wave skew on the producer path).

__global__ __launch_bounds__(256, 1) void lstm_persistent(
    const float* __restrict__ de,  const float* __restrict__ h0,
    const float* __restrict__ c0,
    const float* __restrict__ Wih, const float* __restrict__ Whh,
    const float* __restrict__ bih, const float* __restrict__ bhh,
    float* __restrict__ out, uint32_t* __restrict__ hbuf)
{
    __shared__ uint32_t hlds[4 * 260];     // packed h, [b][d] stride 260
    __shared__ float    glds[256];         // t=0 gates [gate][dim16][b]
    __shared__ float    t0buf[2][4][256];  // e0, h0

    const int tid = threadIdx.x;
    const int grp = blockIdx.x >> 4;
    const int jb  = blockIdx.x & 15;

    const int w  = tid >> 6;    // wave 0..3 (4 dims each)
    const int l  = tid & 63;
    const int lr = l & 15;      // A/B/D row-col lane index
    const int lg = l >> 4;

    // in-lane output binding
    const int bl = lr & 3;                 // batch in group (cols 4..15 = replicas)
    const int bx = grp * 4 + bl;
    const int dx = jb * 16 + w * 4 + lg;   // this lane's dim
    const bool store_lane = (lr < 4);

    const float bs0 = bih[      dx] + bhh[      dx];
    const float bs1 = bih[256 + dx] + bhh[256 + dx];
    const float bs2 = bih[512 + dx] + bhh[512 + dx];
    const float bs3 = bih[768 + dx] + bhh[768 + dx];
    float c_reg = c0[(size_t)bx * 256 + dx];

    bf16x8 Ahi[8], Alo[8];

    // ---- t = 0: stage e0/h0, scalar dot into glds (verbatim R7) ----
    #pragma unroll
    for (int m = 0; m < 8; ++m) {
        int idx = m * 256 + tid;
        int arr = idx >> 10, bq = (idx >> 8) & 3, k = idx & 255;
        t0buf[arr][bq][k] = arr ? h0[(size_t)(grp * 4 + bq) * 256 + k]
                                : de[(size_t)(grp * 4 + bq) * T_ * D_ + k];
    }
    __syncthreads();
    {
        int r = tid >> 2, bq = tid & 3;
        int gr = (r >> 4) * 256 + jb * 16 + (r & 15);
        const float4* wi4 = (const float4*)(Wih + (size_t)gr * 256);
        const float4* wh4 = (const float4*)(Whh + (size_t)gr * 256);
        const float4* e4  = (const float4*)(&t0buf[0][bq][0]);
        const float4* h4  = (const float4*)(&t0buf[1][bq][0]);
        float a0 = 0.f, a1 = 0.f, a2 = 0.f, a3 = 0.f;
        #pragma unroll 8
        for (int k4 = 0; k4 < 64; ++k4) {
            float4 x = wi4[k4], y = e4[k4];
            a0 += x.x*y.x; a1 += x.y*y.y; a2 += x.z*y.z; a3 += x.w*y.w;
            x = wh4[k4]; y = h4[k4];
            a0 += x.x*y.x; a1 += x.y*y.y; a2 += x.z*y.z; a3 += x.w*y.w;
        }
        glds[(r >> 4) * 64 + (r & 15) * 4 + bq] = (a0 + a1) + (a2 + a3);
    }
    __syncthreads();

    // ---- t = 0 epilogue: in-lane read of glds with the NEW binding ----
    {
        int d16 = w * 4 + lg;
        float gi = glds[      d16 * 4 + bl] + bs0;
        float gf = glds[ 64 + d16 * 4 + bl] + bs1;
        float gg = glds[128 + d16 * 4 + bl] + bs2;
        float go = glds[192 + d16 * 4 + bl] + bs3;
        float si = 1.f / (1.f + __expf(-gi));
        float sf = 1.f / (1.f + __expf(-gf));
        float so = 1.f / (1.f + __expf(-go));
        float tg = 1.f - 2.f / (1.f + __expf(2.f * gg));
        c_reg = sf * c_reg + si * tg;
        float tc = 1.f - 2.f / (1.f + __expf(2.f * c_reg));
        float hn = so * tc;
        if (store_lane) {
            uint32_t pk = ((uint32_t)f2bf(hn) << 16);   // t = 0
            st_cg_u32(hbuf + 0 * 16384 + grp * 1024 + bl * 256 + dx, pk);
            out[((size_t)bx * T_ + 0) * 512 + dx] = hn;
        }
    }

    // ---- one-time: Wc hi/lo A-frags with in-lane row binding ----
    {
        int gr = (lr & 3) * 256 + jb * 16 + w * 4 + (lr >> 2);
        const float4* wi4 = (const float4*)(Wih + (size_t)gr * 256);
        const float4* wh4 = (const float4*)(Whh + (size_t)gr * 256);
        #pragma unroll
        for (int kt = 0; kt < 8; ++kt) {
            float4 p  = wi4[kt * 8 + lg * 2], q  = wi4[kt * 8 + lg * 2 + 1];
            float4 r4 = wh4[kt * 8 + lg * 2], s4 = wh4[kt * 8 + lg * 2 + 1];
            float f[8] = {p.x + r4.x, p.y + r4.y, p.z + r4.z, p.w + r4.w,
                          q.x + s4.x, q.y + s4.y, q.z + s4.z, q.w + s4.w};
            USH hi, lo;
            #pragma unroll
            for (int j = 0; j < 8; ++j) {
                ushort h = f2bf(f[j]);
                hi.s[j] = h;
                lo.s[j] = f2bf(f[j] - bf2f(h));
            }
            Ahi[kt] = hi.v; Alo[kt] = lo.v;
        }
    }

    // ---- steady state ----
    for (int t = 1; t < T_; ++t) {
        // poll h_{t-1} (verbatim R7)
        const uint32_t expc = (uint32_t)(t - 1);
        const uint32_t* hp = hbuf + ((t - 1) & 1) * 16384 + grp * 1024 + tid * 4;
        uint4 v = ldx4u_cg(hp);
        while ((((v.x ^ expc) | (v.y ^ expc) | (v.z ^ expc) | (v.w ^ expc)) & 0xFFFFu) != 0u)
            v = ldx4u_cg(hp);
        *(uint4*)(hlds + (tid >> 6) * 260 + (tid & 63) * 4) = v;
        __syncthreads();

        // B-frags via v_perm + dual-acc MFMA (verbatim R7)
        f32x4 acch = (f32x4){0.f, 0.f, 0.f, 0.f};
        f32x4 accl = (f32x4){0.f, 0.f, 0.f, 0.f};
        const uint32_t* hrow = hlds + (lr & 3) * 260 + lg * 8;
        #pragma unroll
        for (int kt = 0; kt < 8; ++kt) {
            uint4 q0 = *(const uint4*)(hrow + kt * 32);
            uint4 q1 = *(const uint4*)(hrow + kt * 32 + 4);
            UBF bb;
            bb.u[0] = hi2(q0.x, q0.y);
            bb.u[1] = hi2(q0.z, q0.w);
            bb.u[2] = hi2(q1.x, q1.y);
            bb.u[3] = hi2(q1.z, q1.w);
            acch = __builtin_amdgcn_mfma_f32_16x16x32_bf16(Ahi[kt], bb.v, acch, 0, 0, 0);
            accl = __builtin_amdgcn_mfma_f32_16x16x32_bf16(Alo[kt], bb.v, accl, 0, 0, 0);
        }
        f32x4 acc = acch + accl;

        // in-lane epilogue: all 4 gates live in this lane's acc
        {
            float gi = acc[0] + bs0;
            float gf = acc[1] + bs1;
            float gg = acc[2] + bs2;
            float go = acc[3] + bs3;
            float si = 1.f / (1.f + __expf(-gi));
            float sf = 1.f / (1.f + __expf(-gf));
            float so = 1.f / (1.f + __expf(-go));
            float tg = 1.f - 2.f / (1.f + __expf(2.f * gg));
            c_reg = sf * c_reg + si * tg;
            float tc = 1.f - 2.f / (1.f + __expf(2.f * c_reg));
            float hn = so * tc;
            if (store_lane) {
                if (t < T_ - 1) {
                    uint32_t pk = ((uint32_t)f2bf(hn) << 16) | (uint32_t)t;
                    st_cg_u32(hbuf + (t & 1) * 16384 + grp * 1024 + bl * 256 + dx, pk);
                }
                out[((size_t)bx * T_ + t) * 512 + dx] = hn;
            }
        }
        __syncthreads();   // all hlds reads done before next iteration's staging
    }
}

// ==================== Attention: bf16 MFMA flash (unchanged, verified) ========

__global__ __launch_bounds__(256, 2) void attn_kernel(
    const float* __restrict__ E, float* __restrict__ out)
{
    __shared__ alignas(16) ushort Ech [32 * 264];
    __shared__ alignas(16) ushort EchT[256 * 40];
    __shared__ alignas(16) ushort Phi[4][16 * 40];
    __shared__ alignas(16) ushort Plo[4][16 * 40];

    const int id  = blockIdx.x;
    const int xcd = id & 7, rr = id >> 3;
    const int tt  = rr & 7,  bh = rr >> 3;
    const int b   = bh * 8 + xcd;
    const int t0  = tt * 64;

    const int tid = threadIdx.x;
    const int w   = tid >> 6;
    const int l   = tid & 63;
    const int lr  = l & 15;
    const int lg  = l >> 4;

    bf16x8 Ahi[8], Alo[8];
    {
        const float* Hrow = out + ((size_t)b * T_ + (t0 + w * 16 + lr)) * 512;
        #pragma unroll
        for (int kt = 0; kt < 8; ++kt) {
            float4 x0 = *(const float4*)(Hrow + kt * 32 + lg * 8);
            float4 x1 = *(const float4*)(Hrow + kt * 32 + lg * 8 + 4);
            float f[8] = {x0.x, x0.y, x0.z, x0.w, x1.x, x1.y, x1.z, x1.w};
            USH hi, lo;
            #pragma unroll
            for (int j = 0; j < 8; ++j) {
                ushort h = f2bf(f[j]);
                hi.s[j] = h;
                lo.s[j] = f2bf(f[j] - bf2f(h));
            }
            Ahi[kt] = hi.v; Alo[kt] = lo.v;
        }
    }

    f32x4 ctx[16];
    #pragma unroll
    for (int i = 0; i < 16; ++i) ctx[i] = (f32x4){0.f, 0.f, 0.f, 0.f};
    float mrow[4] = {-1e30f, -1e30f, -1e30f, -1e30f};
    float srow[4] = {0.f, 0.f, 0.f, 0.f};

    const float* Eb = E + (size_t)b * S_ * 256;

    for (int c = 0; c < 16; ++c) {
        #pragma unroll
        for (int m = 0; m < 8; ++m) {
            int idx = m * 256 + tid;
            int sr = idx >> 6, k4 = idx & 63;
            float4 e = *(const float4*)(Eb + (size_t)(c * 32 + sr) * 256 + 4 * k4);
            ushort4 u;
            u.x = f2bf(e.x); u.y = f2bf(e.y); u.z = f2bf(e.z); u.w = f2bf(e.w);
            *(ushort4*)(&Ech[sr * 264 + 4 * k4]) = u;
        }
        __syncthreads();

        f32x4 sacc0 = (f32x4){0.f,0.f,0.f,0.f};
        f32x4 sacc1 = (f32x4){0.f,0.f,0.f,0.f};
        #pragma unroll
        for (int kt = 0; kt < 8; ++kt) {
            bf16x8 Bf0 = *(const bf16x8*)(&Ech[(0 * 16 + lr) * 264 + kt * 32 + lg * 8]);
            bf16x8 Bf1 = *(const bf16x8*)(&Ech[(1 * 16 + lr) * 264 + kt * 32 + lg * 8]);
            sacc0 = __builtin_amdgcn_mfma_f32_16x16x32_bf16(Ahi[kt], Bf0, sacc0, 0, 0, 0);
            sacc0 = __builtin_amdgcn_mfma_f32_16x16x32_bf16(Alo[kt], Bf0, sacc0, 0, 0, 0);
            sacc1 = __builtin_amdgcn_mfma_f32_16x16x32_bf16(Ahi[kt], Bf1, sacc1, 0, 0, 0);
            sacc1 = __builtin_amdgcn_mfma_f32_16x16x32_bf16(Alo[kt], Bf1, sacc1, 0, 0, 0);
        }

        #pragma unroll
        for (int m = 0; m < 8; ++m) {
            int idx = m * 256 + tid;
            int s = idx & 31, kq = idx >> 5;
            ushort4 v = *(const ushort4*)(&Ech[s * 264 + 4 * kq]);
            EchT[(4 * kq + 0) * 40 + s] = v.x;
            EchT[(4 * kq + 1) * 40 + s] = v.y;
            EchT[(4 * kq + 2) * 40 + s] = v.z;
            EchT[(4 * kq + 3) * 40 + s] = v.w;
        }

        float cmax[4], p0[4], p1[4], csum[4], mnew[4], scale[4];
        #pragma unroll
        for (int g = 0; g < 4; ++g) cmax[g] = fmaxf(sacc0[g], sacc1[g]);
        #pragma unroll
        for (int d = 1; d < 16; d <<= 1) {
            #pragma unroll
            for (int g = 0; g < 4; ++g) cmax[g] = fmaxf(cmax[g], __shfl_xor(cmax[g], d));
        }
        #pragma unroll
        for (int g = 0; g < 4; ++g) {
            mnew[g]  = fmaxf(mrow[g], cmax[g]);
            scale[g] = __expf(mrow[g] - mnew[g]);
            p0[g] = __expf(sacc0[g] - mnew[g]);
            p1[g] = __expf(sacc1[g] - mnew[g]);
            csum[g] = p0[g] + p1[g];
        }
        #pragma unroll
        for (int d = 1; d < 16; d <<= 1) {
            #pragma unroll
            for (int g = 0; g < 4; ++g) csum[g] += __shfl_xor(csum[g], d);
        }
        #pragma unroll
        for (int g = 0; g < 4; ++g) {
            srow[g] = srow[g] * scale[g] + csum[g];
            mrow[g] = mnew[g];
        }
        #pragma unroll
        for (int i = 0; i < 16; ++i) {
            ctx[i][0] *= scale[0]; ctx[i][1] *= scale[1];
            ctx[i][2] *= scale[2]; ctx[i][3] *= scale[3];
        }
        #pragma unroll
        for (int g = 0; g < 4; ++g) {
            int rrw = (lg * 4 + g) * 40;
            ushort h0v = f2bf(p0[g]);
            Phi[w][rrw + lr]      = h0v;
            Plo[w][rrw + lr]      = f2bf(p0[g] - bf2f(h0v));
            ushort h1v = f2bf(p1[g]);
            Phi[w][rrw + 16 + lr] = h1v;
            Plo[w][rrw + 16 + lr] = f2bf(p1[g] - bf2f(h1v));
        }
        __syncthreads();

        {
            bf16x8 Ap = *(const bf16x8*)(&Phi[w][lr * 40 + lg * 8]);
            bf16x8 Aq = *(const bf16x8*)(&Plo[w][lr * 40 + lg * 8]);
            #pragma unroll
            for (int dt = 0; dt < 16; ++dt) {
                bf16x8 Bf = *(const bf16x8*)(&EchT[(dt * 16 + lr) * 40 + lg * 8]);
                ctx[dt] = __builtin_amdgcn_mfma_f32_16x16x32_bf16(Ap, Bf, ctx[dt], 0, 0, 0);
                ctx[dt] = __builtin_amdgcn_mfma_f32_16x16x32_bf16(Aq, Bf, ctx[dt], 0, 0, 0);
            }
        }
        __syncthreads();
    }

    float inv[4];
    #pragma unroll
    for (int g = 0; g < 4; ++g) inv[g] = 1.f / srow[g];
    #pragma unroll
    for (int dt = 0; dt < 16; ++dt) {
        #pragma unroll
        for (int g = 0; g < 4; ++g) {
            out[((size_t)b * T_ + (t0 + w * 16 + lg * 4 + g)) * 512 + 256 + dt * 16 + lr] =
                ctx[dt][g] * inv[g];
        }
    }
}

// -------------------- launch --------------------

extern "C" void kernel_launch(void* const* d_in, const int* in_sizes, int n_in,
                              void* d_out, int out_size, void* d_ws, size_t ws_size,
                              hipStream_t stream)
{
    const float* de  = (const float*)d_in[0];
    const float* h0  = (const float*)d_in[1];
    const float* c0  = (const float*)d_in[2];
    const float* E   = (const float*)d_in[3];
    const float* Wih = (const float*)d_in[4];
    const float* Whh = (const float*)d_in[5];
    const float* bih = (const float*)d_in[6];
    const float* bhh = (const float*)d_in[7];
    float* out  = (float*)d_out;
    uint32_t* hbuf = (uint32_t*)d_ws;

    ws_init<<<128, 256, 0, stream>>>(hbuf);

    void* args[] = {(void*)&de, (void*)&h0, (void*)&c0, (void*)&Wih, (void*)&Whh,
                    (void*)&bih, (void*)&bhh, (void*)&out, (void*)&hbuf};
    hipLaunchCooperativeKernel((const void*)lstm_persistent,
                               dim3(GROUPS * BPG), dim3(256), args, 0, stream);

    attn_kernel<<<dim3(512), 256, 0, stream>>>(E, out);
}